// Round 1
// baseline (171.766 us; speedup 1.0000x reference)
//
#include <hip/hip_runtime.h>
#include <math.h>

// BasicBlockA: masked conv (L*C out) + bias + ELU -> grouped masked conv -> mean over L + residual.
// Fully fused: one block = one 32x32 output tile of one batch image.
// Mask analysis: kernel row ky=2 is always zero; row ky=1 keeps kx=0 always and kx=1 iff j<=i.
// => loops run over ky in {0,1} only, 42/81 taps live.

namespace {
constexpr int NC = 3, NH = 128, NW = 128, NL = 16;
constexpr int TILE = 32;
constexpr int XR = 34, XC = 40;  // x tile: rows (oy0-2 .. oy0+31), 40-col stride, 3ch interleaved
constexpr int HR = 33, HC = 36;  // h tile: rows (oy0-1 .. oy0+31), 36-col stride, 3ch interleaved
constexpr int WPL = 54;          // packed weights per latent: [i][j][ky<2][kx<3]
}

__device__ __forceinline__ float softplusf(float v) {
    return v > 20.f ? v : log1pf(expf(v));
}

// Build masked weights into d_ws: wb[0..863] = w1 packed, wb[864..1727] = w2 packed.
// Packed layout [l][i][j][ky(2)][kx(3)]; the always-masked ky==2 row is dropped.
__global__ void prep_weights(const float* __restrict__ w1, const float* __restrict__ c1,
                             const float* __restrict__ w2, const float* __restrict__ c2,
                             float* __restrict__ wb) {
    int e = blockIdx.x * blockDim.x + threadIdx.x;
    if (e >= NL * NC * NC * 2 * 3) return;
    int kx = e % 3;
    int ky = (e / 3) % 2;
    int j  = (e / 6) % 3;
    int i  = (e / 18) % 3;
    int l  = e / WPL;
    int g = l * 81 + i * 27 + j * 9 + ky * 3 + kx;  // [L,C,C,3,3] global index
    bool used   = (ky == 0) || (kx == 0) || (kx == 1 && j <= i);
    bool center = (i == j) && (ky == 1) && (kx == 1);
    wb[e]       = used ? (center ? softplusf(c1[g]) : w1[g]) : 0.f;
    wb[864 + e] = used ? (center ? softplusf(c2[g]) : w2[g]) : 0.f;
}

__global__ __launch_bounds__(256, 4) void fused_block(
    const float* __restrict__ x, const float* __restrict__ bias1,
    const float* __restrict__ res, const float* __restrict__ wb,
    float* __restrict__ out)
{
    __shared__ alignas(16) float xs[XR * XC * 3];
    __shared__ alignas(16) float hs[HR * HC * 3];

    const int tid = threadIdx.x;
    const int b   = blockIdx.z;
    const int oy0 = blockIdx.y * TILE;
    const int ox0 = blockIdx.x * TILE;

    // ---- load x tile: planar (coalesced) global reads, channel-interleaved LDS store ----
    const float* xb = x + b * NC * NH * NW;
    for (int idx = tid; idx < XR * XC * 3; idx += 256) {
        int lx = idx % XC;
        int ly = (idx / XC) % XR;
        int c  = idx / (XC * XR);
        int gy = oy0 - 2 + ly, gx = ox0 - 2 + lx;
        float v = 0.f;
        if (gy >= 0 && gy < NH && gx >= 0 && gx < NW)
            v = xb[c * NH * NW + gy * NW + gx];
        xs[(ly * XC + lx) * 3 + c] = v;
    }

    const int ty = tid >> 3;       // output row within tile (0..31)
    const int tx = (tid & 7) * 4;  // output col, 1x4 chunk per thread
    float acc[3][4] = {{0.f}};

    #pragma unroll 1
    for (int l = 0; l < NL; ++l) {
        // stage-1 weights: only the 42 live taps are loaded (rest DCE'd)
        float w1r[3][3][2][3];
        #pragma unroll
        for (int i = 0; i < 3; ++i)
        #pragma unroll
        for (int j = 0; j < 3; ++j)
        #pragma unroll
        for (int ky = 0; ky < 2; ++ky)
        #pragma unroll
        for (int kx = 0; kx < 3; ++kx)
            if (ky == 0 || kx == 0 || (kx == 1 && j <= i))
                w1r[i][j][ky][kx] = wb[l * WPL + i * 18 + j * 6 + ky * 3 + kx];
        float br[3];
        #pragma unroll
        for (int i = 0; i < 3; ++i) br[i] = bias1[l * 3 + i];

        __syncthreads();  // prev latent's stage-2 reads done -> hs writable; xs ready at l==0

        // ---- stage 1: h = elu(conv(x, w1[l]) + b1[l]) on HR x 34 positions ----
        for (int chk = tid; chk < HR * 9; chk += 256) {
            int r  = chk / 9;          // h row (image row oy0-1+r)
            int c0 = (chk % 9) * 4;    // h col chunk (image col ox0-1+c0 ..)
            float pre[3][4];
            #pragma unroll
            for (int i = 0; i < 3; ++i)
                #pragma unroll
                for (int p = 0; p < 4; ++p) pre[i][p] = br[i];
            #pragma unroll
            for (int ky = 0; ky < 2; ++ky) {
                const float* xrow = &xs[((r + ky) * XC + c0) * 3];  // 48B-aligned
                float4 v0 = ((const float4*)xrow)[0];
                float4 v1 = ((const float4*)xrow)[1];
                float4 v2 = ((const float4*)xrow)[2];
                float4 v3 = ((const float4*)xrow)[3];
                float2 v4 = ((const float2*)xrow)[8];
                float xv[18] = {v0.x, v0.y, v0.z, v0.w, v1.x, v1.y, v1.z, v1.w,
                                v2.x, v2.y, v2.z, v2.w, v3.x, v3.y, v3.z, v3.w,
                                v4.x, v4.y};
                #pragma unroll
                for (int i = 0; i < 3; ++i)
                #pragma unroll
                for (int j = 0; j < 3; ++j)
                #pragma unroll
                for (int kx = 0; kx < 3; ++kx) {
                    if (ky == 1 && !(kx == 0 || (kx == 1 && j <= i))) continue;
                    float w = w1r[i][j][ky][kx];
                    #pragma unroll
                    for (int p = 0; p < 4; ++p)
                        pre[i][p] += w * xv[(kx + p) * 3 + j];
                }
            }
            // ELU; zero h outside the image (stage-2's conv padding)
            int gy = oy0 - 1 + r;
            bool rok = (gy >= 0 && gy < NH);
            float hv[12];
            #pragma unroll
            for (int p = 0; p < 4; ++p) {
                int gx = ox0 - 1 + c0 + p;
                bool ok = rok && (gx >= 0) && (gx < NW);
                #pragma unroll
                for (int i = 0; i < 3; ++i) {
                    float v = pre[i][p];
                    v = v > 0.f ? v : (__expf(v) - 1.f);
                    hv[p * 3 + i] = ok ? v : 0.f;
                }
            }
            float* hrow = &hs[(r * HC + c0) * 3];
            ((float4*)hrow)[0] = make_float4(hv[0], hv[1], hv[2],  hv[3]);
            ((float4*)hrow)[1] = make_float4(hv[4], hv[5], hv[6],  hv[7]);
            ((float4*)hrow)[2] = make_float4(hv[8], hv[9], hv[10], hv[11]);
        }

        // stage-2 weights: issue loads before the barrier so they overlap it
        float w2r[3][3][2][3];
        #pragma unroll
        for (int i = 0; i < 3; ++i)
        #pragma unroll
        for (int j = 0; j < 3; ++j)
        #pragma unroll
        for (int ky = 0; ky < 2; ++ky)
        #pragma unroll
        for (int kx = 0; kx < 3; ++kx)
            if (ky == 0 || kx == 0 || (kx == 1 && j <= i))
                w2r[i][j][ky][kx] = wb[864 + l * WPL + i * 18 + j * 6 + ky * 3 + kx];

        __syncthreads();  // hs ready

        // ---- stage 2: acc += conv(h, w2[l]) at this thread's 1x4 outputs ----
        #pragma unroll
        for (int ky = 0; ky < 2; ++ky) {
            const float* hrow = &hs[((ty + ky) * HC + tx) * 3];
            float4 v0 = ((const float4*)hrow)[0];
            float4 v1 = ((const float4*)hrow)[1];
            float4 v2 = ((const float4*)hrow)[2];
            float4 v3 = ((const float4*)hrow)[3];
            float2 v4 = ((const float2*)hrow)[8];
            float hvv[18] = {v0.x, v0.y, v0.z, v0.w, v1.x, v1.y, v1.z, v1.w,
                             v2.x, v2.y, v2.z, v2.w, v3.x, v3.y, v3.z, v3.w,
                             v4.x, v4.y};
            #pragma unroll
            for (int i = 0; i < 3; ++i)
            #pragma unroll
            for (int j = 0; j < 3; ++j)
            #pragma unroll
            for (int kx = 0; kx < 3; ++kx) {
                if (ky == 1 && !(kx == 0 || (kx == 1 && j <= i))) continue;
                float w = w2r[i][j][ky][kx];
                #pragma unroll
                for (int p = 0; p < 4; ++p)
                    acc[i][p] += w * hvv[(kx + p) * 3 + j];
            }
        }
    }

    // ---- epilogue: out = acc/L + res*gate*x ----
    float rv = res[0];
    float rg = rv > 0.f ? rv : 0.f;
    const int gy = oy0 + ty;
    float* ob = out + b * NC * NH * NW;
    #pragma unroll
    for (int i = 0; i < 3; ++i) {
        float4 o;
        o.x = acc[i][0] * (1.f / 16.f) + rg * xs[((ty + 2) * XC + tx + 2 + 0) * 3 + i];
        o.y = acc[i][1] * (1.f / 16.f) + rg * xs[((ty + 2) * XC + tx + 2 + 1) * 3 + i];
        o.z = acc[i][2] * (1.f / 16.f) + rg * xs[((ty + 2) * XC + tx + 2 + 2) * 3 + i];
        o.w = acc[i][3] * (1.f / 16.f) + rg * xs[((ty + 2) * XC + tx + 2 + 3) * 3 + i];
        *(float4*)(ob + i * NH * NW + gy * NW + ox0 + tx) = o;
    }
}

extern "C" void kernel_launch(void* const* d_in, const int* in_sizes, int n_in,
                              void* d_out, int out_size, void* d_ws, size_t ws_size,
                              hipStream_t stream) {
    (void)in_sizes; (void)n_in; (void)out_size; (void)ws_size;
    const float* x   = (const float*)d_in[0];
    const float* w1  = (const float*)d_in[1];
    const float* c1  = (const float*)d_in[2];
    const float* b1  = (const float*)d_in[3];
    const float* w2  = (const float*)d_in[4];
    const float* c2  = (const float*)d_in[5];
    const float* res = (const float*)d_in[6];
    float* out = (float*)d_out;
    float* wb  = (float*)d_ws;  // 1728 floats of masked packed weights

    hipLaunchKernelGGL(prep_weights, dim3(4), dim3(256), 0, stream, w1, c1, w2, c2, wb);
    hipLaunchKernelGGL(fused_block, dim3(4, 4, 64), dim3(256), 0, stream,
                       x, b1, res, wb, out);
}